// Round 3
// baseline (1379.272 us; speedup 1.0000x reference)
//
#include <hip/hip_runtime.h>
#include <math.h>

#define F_IN   500
#define H_DIM  64
#define C_DIM  40
#define K_STEPS 10
#define ALPHA  0.1f
#define ROWB   64     // fp8 state: bytes per row (40 payload + 24 pad) = 1 cacheline

typedef float vf4 __attribute__((ext_vector_type(4)));
typedef _Float16 h2 __attribute__((ext_vector_type(2)));

// ---------------------------------------------------------------------------
// fp8 e4m3 encode/decode via exact fp16-pattern equivalence:
//   value(e4m3 byte b) / 256 == fp16 with bits (sign<<15 | (b&0x7f)<<7)
// (exact for normals AND subnormals; e4m3fn has no inf; we never encode NaN).
// ---------------------------------------------------------------------------
__device__ __forceinline__ unsigned enc_fp8(float v) {
    v = fminf(fmaxf(v, -440.f), 440.f);
    _Float16 h = (_Float16)(v * (1.f / 256.f));          // RN to fp16
    unsigned short u = __builtin_bit_cast(unsigned short, h);
    unsigned mag = u & 0x7fffu;
    unsigned r = (mag + 0x3Fu + ((mag >> 7) & 1u)) >> 7; // RNE of low 7 bits
    if (r > 127u) r = 127u;
    return ((u >> 8) & 0x80u) | r;
}

// decode 4 packed e4m3 bytes -> float4 of (value/256)
__device__ __forceinline__ vf4 dec4(unsigned u) {
    unsigned d02 = ((u & 0x007f007fu) << 7) | ((u & 0x00800080u) << 8); // bytes 0,2
    unsigned v   = u >> 8;
    unsigned d13 = ((v & 0x007f007fu) << 7) | ((v & 0x00800080u) << 8); // bytes 1,3
    h2 a = __builtin_bit_cast(h2, d02);
    h2 b = __builtin_bit_cast(h2, d13);
    vf4 r;
    r.x = (float)a.x; r.y = (float)b.x; r.z = (float)a.y; r.w = (float)b.y;
    return r;
}

// ---------------------------------------------------------------------------
// Fused MLP GEMM: h0 = relu(x@W1+b1)@W2+b2, one 64-row tile per block.
// h0 fp32 row-major; hA8 fp8 e4m3, 64 B padded rows (propagation state).
// NOTE (future round): MfmaUtil=0, VALUBusy=35%, 1.6e7 LDS bank conflicts
// (8-way on transposed xs store: 4*LDA1 % 32 == 16) -> direct-row / MFMA.
// ---------------------------------------------------------------------------
#define LDA1 68
__global__ __launch_bounds__(256) void mlp_gemm(
    const float* __restrict__ x, const float* __restrict__ W1,
    const float* __restrict__ b1, const float* __restrict__ W2,
    const float* __restrict__ b2, float* __restrict__ h0,
    unsigned char* __restrict__ hA8, int N)
{
    __shared__ float smem[64 * LDA1 * 2 + H_DIM * C_DIM];
    float* xs  = smem;
    float* ws  = smem + 64 * LDA1;
    float* w2s = smem + 2 * 64 * LDA1;

    const int t    = threadIdx.x;
    const int row0 = blockIdx.x * 64;
    const int tx   = t & 15;
    const int ty   = t >> 4;

    for (int i = t; i < H_DIM * C_DIM; i += 256) w2s[i] = W2[i];

    const float4 b1v = *(const float4*)&b1[tx * 4];

    float acc[4][4];
    #pragma unroll
    for (int i = 0; i < 4; ++i)
        #pragma unroll
        for (int j = 0; j < 4; ++j) acc[i][j] = 0.f;

    for (int k0 = 0; k0 < F_IN; k0 += 64) {
        __syncthreads();
        #pragma unroll
        for (int i = 0; i < 4; ++i) {
            int f  = t + i * 256;
            int r  = f >> 4;
            int c4 = (f & 15) << 2;
            int grow = row0 + r, gk = k0 + c4;
            float4 v = make_float4(0.f, 0.f, 0.f, 0.f);
            if (grow < N && gk < F_IN)
                v = *(const float4*)&x[(long long)grow * F_IN + gk];
            xs[(c4 + 0) * LDA1 + r] = v.x;
            xs[(c4 + 1) * LDA1 + r] = v.y;
            xs[(c4 + 2) * LDA1 + r] = v.z;
            xs[(c4 + 3) * LDA1 + r] = v.w;
        }
        #pragma unroll
        for (int i = 0; i < 4; ++i) {
            int f  = t + i * 256;
            int r  = f >> 4;
            int c4 = (f & 15) << 2;
            int gk = k0 + r;
            float4 v = make_float4(0.f, 0.f, 0.f, 0.f);
            if (gk < F_IN)
                v = *(const float4*)&W1[(long long)gk * H_DIM + c4];
            *(float4*)&ws[r * LDA1 + c4] = v;
        }
        __syncthreads();
        #pragma unroll 8
        for (int kk = 0; kk < 64; ++kk) {
            float4 a4 = *(const float4*)&xs[kk * LDA1 + ty * 4];
            float4 b4 = *(const float4*)&ws[kk * LDA1 + tx * 4];
            const float av[4] = {a4.x, a4.y, a4.z, a4.w};
            const float bv[4] = {b4.x, b4.y, b4.z, b4.w};
            #pragma unroll
            for (int i = 0; i < 4; ++i)
                #pragma unroll
                for (int j = 0; j < 4; ++j)
                    acc[i][j] = fmaf(av[i], bv[j], acc[i][j]);
        }
    }

    __syncthreads();
    #pragma unroll
    for (int i = 0; i < 4; ++i) {
        float4 hv;
        hv.x = fmaxf(acc[i][0] + b1v.x, 0.f);
        hv.y = fmaxf(acc[i][1] + b1v.y, 0.f);
        hv.z = fmaxf(acc[i][2] + b1v.z, 0.f);
        hv.w = fmaxf(acc[i][3] + b1v.w, 0.f);
        *(float4*)&xs[(ty * 4 + i) * LDA1 + tx * 4] = hv;
    }
    __syncthreads();

    for (int o = t; o < 64 * C_DIM; o += 256) {
        int r = o / C_DIM;
        int c = o - r * C_DIM;
        float s = b2[c];
        #pragma unroll 16
        for (int j = 0; j < H_DIM; ++j)
            s = fmaf(xs[r * LDA1 + j], w2s[j * C_DIM + c], s);
        int grow = row0 + r;
        if (grow < N) {
            h0[(long long)grow * C_DIM + c] = s;
            hA8[(size_t)grow * ROWB + c] = (unsigned char)enc_fp8(s);
        }
    }
}

// ---------------------------------------------------------------------------
// Degree / normalization
// ---------------------------------------------------------------------------
__global__ void deg_init(float* __restrict__ deg, int N) {
    int i = blockIdx.x * 256 + threadIdx.x;
    if (i < N) deg[i] = 1.0f;               // self-loop
}

__global__ void deg_count(const int* __restrict__ dst, float* __restrict__ deg, int E) {
    int e = blockIdx.x * 256 + threadIdx.x;
    if (e < E) atomicAdd(&deg[dst[e]], 1.0f);
}

__global__ void dinv_kernel(float* __restrict__ deg, int* __restrict__ lengths, int N) {
    int i = blockIdx.x * 256 + threadIdx.x;
    if (i < N) {
        float d = deg[i];
        deg[i] = 1.0f / sqrtf(d);
        lengths[i] = (int)(d - 0.5f);
    }
}

// ---------------------------------------------------------------------------
// Exclusive prefix scan of row lengths -> row_ptr  (3-kernel block scan)
// ---------------------------------------------------------------------------
__global__ void scan1(const int* __restrict__ len, int* __restrict__ rp,
                      int* __restrict__ bsums, int N) {
    __shared__ int tmp[256];
    int tid = threadIdx.x;
    int gid = blockIdx.x * 256 + tid;
    int v = (gid < N) ? len[gid] : 0;
    tmp[tid] = v;
    __syncthreads();
    for (int off = 1; off < 256; off <<= 1) {
        int t = (tid >= off) ? tmp[tid - off] : 0;
        __syncthreads();
        tmp[tid] += t;
        __syncthreads();
    }
    if (gid < N) rp[gid] = tmp[tid] - v;
    if (tid == 255) bsums[blockIdx.x] = tmp[tid];
}

__global__ void scan2(int* __restrict__ bsums, int nb) {
    __shared__ int tmp[512];
    int tid = threadIdx.x;
    int v = (tid < nb) ? bsums[tid] : 0;
    tmp[tid] = v;
    __syncthreads();
    for (int off = 1; off < 512; off <<= 1) {
        int t = (tid >= off) ? tmp[tid - off] : 0;
        __syncthreads();
        tmp[tid] += t;
        __syncthreads();
    }
    if (tid < nb) bsums[tid] = tmp[tid] - v;
}

__global__ void scan3(int* __restrict__ rp, const int* __restrict__ bsums,
                      int* __restrict__ cursor, int N, int E) {
    int gid = blockIdx.x * 256 + threadIdx.x;
    if (gid < N) {
        int v = rp[gid] + bsums[blockIdx.x];
        rp[gid] = v;
        cursor[gid] = v;
    }
    if (gid == 0) rp[N] = E;
}

// ---------------------------------------------------------------------------
// CSR fill (direct scatter): earr[pos] = src | wq<<17,
// wq = round(dinv[src]*32767) (15-bit quantized, ~1e-4 rel err).
// ---------------------------------------------------------------------------
__global__ void csr_fill_direct(const int* __restrict__ src, const int* __restrict__ dst,
                                const float* __restrict__ dinv,
                                int* __restrict__ cursor, int* __restrict__ earr, int E) {
    int e = blockIdx.x * 256 + threadIdx.x;
    if (e >= E) return;
    int s = src[e];
    int d = dst[e];
    int pos = atomicAdd(&cursor[d], 1);
    unsigned wq = (unsigned)(dinv[s] * 32767.f + 0.5f);
    earr[pos] = (int)((unsigned)s | (wq << 17));
}

// ---------------------------------------------------------------------------
// PPR step v6: fp8 e4m3 state, 64 B padded rows -> EXACTLY 1 line per edge.
// Round-2 model: prop time ~= 44-55 us per (line/edge) per step (per-CU
// gathered-line throughput wall, location-independent). fp16=2 lines=109us;
// fp8-padded=1 line -> predicted 60-85 us/step.
// Wave layout (proven): 4 edge-groups x 16 lanes; q-lane reads dword q of the
// 64 B row (q>=10 clamps to 9, dup lanes coalesce; their accs are discarded).
// Decode: e4m3 -> fp16-pattern bit trick (exact); scale 256 folded into w.
// Accumulation fp32; h0 fp32; LAST step writes fp32 to hout32 (so per-value
// fp8 rounding never reaches the output, only its /sqrt(d)-averaged form).
// ---------------------------------------------------------------------------
__global__ __launch_bounds__(256) void prop8(
    const unsigned char* __restrict__ hin, const float* __restrict__ h0,
    const float* __restrict__ dinv, const int* __restrict__ rp,
    const int* __restrict__ earr,
    unsigned char* __restrict__ hout, float* __restrict__ hout32, int N)
{
    const int wave = threadIdx.x >> 6;
    const int lane = threadIdx.x & 63;
    const int row  = blockIdx.x * 4 + wave;
    if (row >= N) return;

    const int rs = rp[row];
    const int re = rp[row + 1];
    const float dr     = dinv[row];
    const float factor = (1.0f - ALPHA) * dr;
    const int e4 = lane >> 4;                 // edge subgroup 0..3
    const int q  = lane & 15;
    const int qc = (q < 10) ? q : 9;          // clamp; dup lanes coalesce

    const float invq256 = 256.f / 32767.f;    // weight dequant * fp8 scale
    vf4 a0 = {0.f, 0.f, 0.f, 0.f};
    vf4 a1 = {0.f, 0.f, 0.f, 0.f};

    for (int base = rs; base < re; base += 64) {
        int ee = base + lane;
        int p = 0;
        if (ee < re) p = __builtin_nontemporal_load(&earr[ee]);  // padded: p=0 -> w=0
        int cnt = re - base; if (cnt > 64) cnt = 64;
        for (int i = 0; i < cnt; i += 8) {
            int p0 = __shfl(p, i + e4);
            int p1 = __shfl(p, i + 4 + e4);
            int   s0 = (int)((unsigned)p0 & 0x1FFFFu);
            int   s1 = (int)((unsigned)p1 & 0x1FFFFu);
            float w0 = (float)((unsigned)p0 >> 17) * invq256;
            float w1 = (float)((unsigned)p1 >> 17) * invq256;
            const unsigned u0 = *(const unsigned*)(hin + ((size_t)s0 << 6) + (qc << 2));
            const unsigned u1 = *(const unsigned*)(hin + ((size_t)s1 << 6) + (qc << 2));
            const vf4 v0 = dec4(u0);
            const vf4 v1 = dec4(u1);
            a0.x = fmaf(w0, v0.x, a0.x);
            a0.y = fmaf(w0, v0.y, a0.y);
            a0.z = fmaf(w0, v0.z, a0.z);
            a0.w = fmaf(w0, v0.w, a0.w);
            a1.x = fmaf(w1, v1.x, a1.x);
            a1.y = fmaf(w1, v1.y, a1.y);
            a1.z = fmaf(w1, v1.z, a1.z);
            a1.w = fmaf(w1, v1.w, a1.w);
        }
    }

    vf4 acc = a0 + a1;
    // reduce over the 4 edge-subgroups; channel-slot classes (q) stay separate
    acc.x += __shfl_xor(acc.x, 16);
    acc.y += __shfl_xor(acc.y, 16);
    acc.z += __shfl_xor(acc.z, 16);
    acc.w += __shfl_xor(acc.w, 16);
    acc.x += __shfl_xor(acc.x, 32);
    acc.y += __shfl_xor(acc.y, 32);
    acc.z += __shfl_xor(acc.z, 32);
    acc.w += __shfl_xor(acc.w, 32);

    if (lane < 10) {
        const unsigned us = *(const unsigned*)(hin + ((size_t)row << 6) + (lane << 2));
        const vf4 hv = dec4(us);              // value/256
        const float dr256 = dr * 256.f;
        const float4 h0v = *(const float4*)&h0[(size_t)row * C_DIM + lane * 4];
        vf4 o;
        o.x = fmaf(factor, acc.x + dr256 * hv.x, ALPHA * h0v.x);
        o.y = fmaf(factor, acc.y + dr256 * hv.y, ALPHA * h0v.y);
        o.z = fmaf(factor, acc.z + dr256 * hv.z, ALPHA * h0v.z);
        o.w = fmaf(factor, acc.w + dr256 * hv.w, ALPHA * h0v.w);
        if (hout32) {
            *(float4*)&hout32[(size_t)row * C_DIM + lane * 4] =
                make_float4(o.x, o.y, o.z, o.w);
        } else {
            unsigned ob = enc_fp8(o.x) | (enc_fp8(o.y) << 8) |
                          (enc_fp8(o.z) << 16) | (enc_fp8(o.w) << 24);
            *(unsigned*)(hout + ((size_t)row << 6) + (lane << 2)) = ob;
        }
    }
}

// ---------------------------------------------------------------------------
// Row-wise log_softmax over 40 channels (wave per row), fp32 in-place
// ---------------------------------------------------------------------------
__global__ __launch_bounds__(256) void lsm_kernel(float* __restrict__ buf, int N) {
    const int wave = threadIdx.x >> 6;
    const int lane = threadIdx.x & 63;
    const int row  = blockIdx.x * 4 + wave;
    if (row >= N) return;

    float v = (lane < C_DIM) ? buf[(size_t)row * C_DIM + lane] : -INFINITY;
    float m = v;
    for (int off = 32; off; off >>= 1) m = fmaxf(m, __shfl_xor(m, off));
    float e = (lane < C_DIM) ? expf(v - m) : 0.f;
    float s = e;
    for (int off = 32; off; off >>= 1) s += __shfl_xor(s, off);
    if (lane < C_DIM) buf[(size_t)row * C_DIM + lane] = (v - m) - logf(s);
}

// ---------------------------------------------------------------------------
extern "C" void kernel_launch(void* const* d_in, const int* in_sizes, int n_in,
                              void* d_out, int out_size, void* d_ws, size_t ws_size,
                              hipStream_t stream) {
    const float* x  = (const float*)d_in[0];
    const float* W1 = (const float*)d_in[1];
    const float* b1 = (const float*)d_in[2];
    const float* W2 = (const float*)d_in[3];
    const float* b2 = (const float*)d_in[4];
    const int* ei = (const int*)d_in[5];   // int32 per harness contract

    const int N = in_sizes[0] / F_IN;          // 100000
    const int E = in_sizes[5] / 2;             // 3200000
    const int* src = ei;
    const int* dst = ei + E;
    float* out = (float*)d_out;

    char* w = (char*)d_ws;
    float*         h0   = (float*)w;         w += (size_t)N * C_DIM * 4;  // 16 MB fp32
    unsigned char* s8A  = (unsigned char*)w; w += (size_t)N * ROWB;       // 6.4 MB fp8 ping
    unsigned char* s8B  = (unsigned char*)w; w += (size_t)N * ROWB;       // 6.4 MB fp8 pong
    float* dinv  = (float*)w;  w += (size_t)N * 4;           // deg -> dinv in place
    int*   rp    = (int*)w;    w += (size_t)(N + 1) * 4;
    int*   cursor= (int*)w;    w += (size_t)N * 4;           // lengths, then cursor
    int*   bsums = (int*)w;    w += (size_t)512 * 4;
    int*   earr  = (int*)w;    w += (size_t)E * 4;           // 12.8 MB packed edges

    const int nbN = (N + 255) / 256;
    const int nbE = (E + 255) / 256;
    const int nbRow = (N + 3) / 4;
    const int nbGemm = (N + 63) / 64;

    mlp_gemm<<<nbGemm, 256, 0, stream>>>(x, W1, b1, W2, b2, h0, s8A, N);

    deg_init <<<nbN, 256, 0, stream>>>(dinv, N);
    deg_count<<<nbE, 256, 0, stream>>>(dst, dinv, E);
    dinv_kernel<<<nbN, 256, 0, stream>>>(dinv, cursor, N);

    scan1<<<nbN, 256, 0, stream>>>(cursor, rp, bsums, N);
    scan2<<<1, 512, 0, stream>>>(bsums, nbN);
    scan3<<<nbN, 256, 0, stream>>>(rp, bsums, cursor, N, E);

    csr_fill_direct<<<nbE, 256, 0, stream>>>(src, dst, dinv, cursor, earr, E);

    // ping-pong fp8 state; steps 0..8 write fp8, step 9 writes fp32 to out
    unsigned char* pa = s8A;
    unsigned char* pb = s8B;
    for (int k = 0; k < K_STEPS; ++k) {
        const int last = (k == K_STEPS - 1);
        prop8<<<nbRow, 256, 0, stream>>>(pa, h0, dinv, rp, earr,
                                         pb, last ? out : nullptr, N);
        unsigned char* t = pa; pa = pb; pb = t;
    }

    lsm_kernel<<<nbRow, 256, 0, stream>>>(out, N);
}